// Round 8
// baseline (245.320 us; speedup 1.0000x reference)
//
#include <hip/hip_runtime.h>
#include <hip/hip_fp16.h>
#include <math.h>

// Problem constants (fixed by reference setup_inputs)
#define NN 50000      // nodes
#define NE 800000     // edges
#define D  128        // d_in
#define D3 384        // 3*d_in
#define DO 64         // d_out

typedef _Float16 f16x2 __attribute__((ext_vector_type(2)));

__device__ __forceinline__ float dot2acc(unsigned int h2bits, f16x2 w, float acc) {
#if __has_builtin(__builtin_amdgcn_fdot2)
  return __builtin_amdgcn_fdot2(__builtin_bit_cast(f16x2, h2bits), w, acc, false);
#else
  __half2 h = __builtin_bit_cast(__half2, h2bits);
  float2 hf = __half22float2(h);
  return acc + hf.x * (float)w[0] + hf.y * (float)w[1];
#endif
}

// ---------------- setup: fused GRU (blocks 0..63) + init packed (blocks 64..) ------
__global__ __launch_bounds__(256) void setup_kernel(
    const float* __restrict__ init_w, const float* __restrict__ w_ih,
    const float* __restrict__ w_hh, const float* __restrict__ b_ih,
    const float* __restrict__ b_hh, float* __restrict__ W,
    unsigned long long* __restrict__ packed, int* __restrict__ total) {
  if (blockIdx.x >= 64) {
    int i = (blockIdx.x - 64) * 256 + threadIdx.x;
    if (i < NN) packed[i] = (1ULL << 32);  // deg = 1.0 fixed-point, count = 0
    if (i == 0) *total = 0;
    return;
  }
  int idx = blockIdx.x * 256 + threadIdx.x;  // < 16384
  int b = idx >> 7;
  int j = idx & 127;
  const float* xr = init_w + b * D;
  const float* wr_i = w_ih + j * D;
  const float* wz_i = w_ih + (D + j) * D;
  const float* wn_i = w_ih + (2 * D + j) * D;
  const float* wr_h = w_hh + j * D;
  const float* wz_h = w_hh + (D + j) * D;
  const float* wn_h = w_hh + (2 * D + j) * D;
  float ir = 0.f, iz = 0.f, in_ = 0.f, hr = 0.f, hz = 0.f, hn = 0.f;
#pragma unroll 4
  for (int k = 0; k < D; ++k) {
    float xv = xr[k];
    ir += xv * wr_i[k];
    iz += xv * wz_i[k];
    in_ += xv * wn_i[k];
    hr += xv * wr_h[k];
    hz += xv * wz_h[k];
    hn += xv * wn_h[k];
  }
  ir += b_ih[j];       hr += b_hh[j];
  iz += b_ih[D + j];   hz += b_hh[D + j];
  in_ += b_ih[2 * D + j]; hn += b_hh[2 * D + j];
  float r = 1.f / (1.f + expf(-(ir + hr)));
  float z = 1.f / (1.f + expf(-(iz + hz)));
  float n = tanhf(in_ + r * hn);
  W[idx] = (1.f - z) * n + z * init_w[idx];
}

// ---------------- one packed atomic per edge: count + fixed-point degree; rank -----
__global__ __launch_bounds__(256) void count_deg_kernel(const int* __restrict__ col,
                                                        const float* __restrict__ ew,
                                                        unsigned long long* __restrict__ packed,
                                                        int* __restrict__ rank) {
  int e = blockIdx.x * 256 + threadIdx.x;
  if (e < NE) {
    int c = __builtin_nontemporal_load(&col[e]);
    float w = __builtin_nontemporal_load(&ew[e]);
    unsigned long long add = (1ULL << 40) | (unsigned long long)(w * 4294967296.0f);
    unsigned long long old = atomicAdd(&packed[c], add);
    __builtin_nontemporal_store((int)(old >> 40), &rank[e]);
  }
}

// ---------------- dis = rsqrt(deg); cnt; bucket starts padded to x4 ----------------
__global__ __launch_bounds__(256) void dis_scan_kernel(
    const unsigned long long* __restrict__ packed, float* __restrict__ dis,
    int* __restrict__ cnt, int* __restrict__ start, int* __restrict__ total) {
  int i = blockIdx.x * 256 + threadIdx.x;
  int lane = threadIdx.x & 63;
  int c = 0;
  float d = 1.0f;
  if (i < NN) {
    unsigned long long p = packed[i];
    c = (int)(p >> 40);
    d = (float)(p & ((1ULL << 40) - 1)) * 0x1p-32f;
  }
  int cp = (c + 3) & ~3;  // pad buckets to multiple of 4 -> 16B-aligned u32 starts
  int pre = cp;
#pragma unroll
  for (int off = 1; off < 64; off <<= 1) {
    int t = __shfl_up(pre, off, 64);
    if (lane >= off) pre += t;
  }
  int excl = pre - cp;
  int wtot = __shfl(pre, 63, 64);
  int base = 0;
  if (lane == 63) base = atomicAdd(total, wtot);
  base = __shfl(base, 63, 64);
  if (i < NN) {
    start[i] = base + excl;
    cnt[i] = c;
    dis[i] = rsqrtf(fmaxf(d, 1e-12f));  // d >= 1.0 always (self-loop)
  }
}

// ---------------- bucket scatter, NO atomics: epack[slot] = (j:u16 | ew:f16<<16) ---
__global__ __launch_bounds__(256) void bucket_kernel(
    const int* __restrict__ row, const int* __restrict__ col,
    const float* __restrict__ ew, const int* __restrict__ rank,
    const int* __restrict__ start, unsigned int* __restrict__ epack) {
  int e = blockIdx.x * 256 + threadIdx.x;
  if (e >= NE) return;
  int j = __builtin_nontemporal_load(&row[e]);
  int c = __builtin_nontemporal_load(&col[e]);
  float w = __builtin_nontemporal_load(&ew[e]);
  int rk = __builtin_nontemporal_load(&rank[e]);
  unsigned short wb = __builtin_bit_cast(unsigned short, (_Float16)w);
  int slot = start[c] + rk;
  __builtin_nontemporal_store((unsigned int)j | ((unsigned int)wb << 16),
                              &epack[slot]);
}

// ---------------- yw = dis[r] * (x @ W)  -> fp16 (W staged in LDS) -----------------
struct alignas(16) h2x4 { __half2 a, b, c, d; };

__global__ __launch_bounds__(256) void xw_kernel(const float* __restrict__ x,
                                                 const float* __restrict__ W,
                                                 const float* __restrict__ dis,
                                                 __half* __restrict__ ywh) {
  __shared__ float Wl[D * D];  // 64 KB
  for (int i = threadIdx.x; i < D * D; i += 256) Wl[i] = W[i];
  __syncthreads();
  const int t = threadIdx.x;
  const int rr = t >> 4;           // 0..15
  const int c0 = (t & 15) * 8;     // 0..120
  const int ROWS_PER_TILE = 64;
  for (int base = blockIdx.x * ROWS_PER_TILE; base < NN; base += gridDim.x * ROWS_PER_TILE) {
    float acc[4][8];
#pragma unroll
    for (int q = 0; q < 4; ++q)
#pragma unroll
      for (int j = 0; j < 8; ++j) acc[q][j] = 0.f;
    int r0 = base + rr;
#pragma unroll 4
    for (int k = 0; k < D; ++k) {
      float xv[4];
#pragma unroll
      for (int q = 0; q < 4; ++q) {
        int r = r0 + q * 16;
        xv[q] = (r < NN) ? x[(long)r * D + k] : 0.f;
      }
#pragma unroll
      for (int j = 0; j < 8; ++j) {
        float wv = Wl[k * D + c0 + j];
#pragma unroll
        for (int q = 0; q < 4; ++q) acc[q][j] += xv[q] * wv;
      }
    }
#pragma unroll
    for (int q = 0; q < 4; ++q) {
      int r = r0 + q * 16;
      if (r < NN) {
        float ds = dis[r];
        h2x4 pk;
        pk.a = __floats2half2_rn(ds * acc[q][0], ds * acc[q][1]);
        pk.b = __floats2half2_rn(ds * acc[q][2], ds * acc[q][3]);
        pk.c = __floats2half2_rn(ds * acc[q][4], ds * acc[q][5]);
        pk.d = __floats2half2_rn(ds * acc[q][6], ds * acc[q][7]);
        *(h2x4*)(ywh + (long)r * D + c0) = pk;
      }
    }
  }
}

// ---------------- fused: gather (regs) -> relu -> 1KB LDS -> @ lin_w^T + b ---------
// h_i = relu(dis_i * (yw_i + sum ew*yw_j)). One wave per node; lane l holds dims
// (2l,2l+1) during gather; lane o = output channel in projection (lin_w row o in
// 64 VGPRs). launch_bounds(256,4): cap 128 VGPR so lt[] stays in registers.
__global__ __launch_bounds__(256, 4) void gather_out_kernel(
    const int* __restrict__ start, const int* __restrict__ cnt,
    const unsigned int* __restrict__ epack, const float* __restrict__ dis,
    const __half* __restrict__ ywh, const float* __restrict__ lin_w,
    const float* __restrict__ lin_b, float* __restrict__ out) {
  __shared__ unsigned int hb[4][64];  // per-wave packed-half2 h row, 1 KB
  const int wv = threadIdx.x >> 6;
  const int lane = threadIdx.x & 63;
  // lane o caches lin_w row o as 64 half2 registers
  f16x2 lt[64];
  {
    const float* wrow = lin_w + lane * D;
#pragma unroll
    for (int kk = 0; kk < 64; ++kk) {
      float2 wp = *(const float2*)(wrow + 2 * kk);
      f16x2 v;
      v[0] = (_Float16)wp.x;
      v[1] = (_Float16)wp.y;
      lt[kk] = v;
    }
  }
  const float bias = lin_b[lane];
  const __half2* __restrict__ yw2 = (const __half2*)ywh;  // row stride 64
  int gw = blockIdx.x * 4 + wv;
  int nw = gridDim.x * 4;
  for (int i = gw; i < NN; i += nw) {
    // self-loop term: yw_i (weight 1)
    float2 sv = __half22float2(yw2[(long)i * 64 + lane]);
    float a0 = sv.x;
    float a1 = sv.y;
    int s = start[i];          // multiple of 4 -> epack+s is 16B aligned
    int se = s + cnt[i];
    for (; s + 4 <= se; s += 4) {
      uint4 p = *(const uint4*)(epack + s);  // 4 edges
      int j0 = p.x & 0xffff, j1 = p.y & 0xffff, j2 = p.z & 0xffff, j3 = p.w & 0xffff;
      _Float16 w0 = __builtin_bit_cast(_Float16, (unsigned short)(p.x >> 16));
      _Float16 w1 = __builtin_bit_cast(_Float16, (unsigned short)(p.y >> 16));
      _Float16 w2 = __builtin_bit_cast(_Float16, (unsigned short)(p.z >> 16));
      _Float16 w3 = __builtin_bit_cast(_Float16, (unsigned short)(p.w >> 16));
      __half2 v0 = yw2[(long)j0 * 64 + lane];
      __half2 v1 = yw2[(long)j1 * 64 + lane];
      __half2 v2 = yw2[(long)j2 * 64 + lane];
      __half2 v3 = yw2[(long)j3 * 64 + lane];
      // (float)f16 * (float)f16 + f32  ->  v_fma_mix_f32
      a0 += (float)w0 * (float)__low2half(v0) + (float)w1 * (float)__low2half(v1);
      a0 += (float)w2 * (float)__low2half(v2) + (float)w3 * (float)__low2half(v3);
      a1 += (float)w0 * (float)__high2half(v0) + (float)w1 * (float)__high2half(v1);
      a1 += (float)w2 * (float)__high2half(v2) + (float)w3 * (float)__high2half(v3);
    }
    for (; s < se; ++s) {
      unsigned int p = epack[s];
      int j0 = p & 0xffff;
      _Float16 w0 = __builtin_bit_cast(_Float16, (unsigned short)(p >> 16));
      __half2 v0 = yw2[(long)j0 * 64 + lane];
      a0 += (float)w0 * (float)__low2half(v0);
      a1 += (float)w0 * (float)__high2half(v0);
    }
    float ds = dis[i];
    __half2 hv = __floats2half2_rn(fmaxf(ds * a0, 0.f), fmaxf(ds * a1, 0.f));
    hb[wv][lane] = __builtin_bit_cast(unsigned int, hv);
    // same-wave LDS RAW: drain ds_write before reads (no cross-wave sharing)
    asm volatile("s_waitcnt lgkmcnt(0)" ::: "memory");
    float ac0 = bias, ac1 = 0.f, ac2 = 0.f, ac3 = 0.f;
    const uint4* hrow = (const uint4*)&hb[wv][0];
#pragma unroll
    for (int c = 0; c < 16; ++c) {
      uint4 v = hrow[c];  // broadcast read, conflict-free
      ac0 = dot2acc(v.x, lt[4 * c + 0], ac0);
      ac1 = dot2acc(v.y, lt[4 * c + 1], ac1);
      ac2 = dot2acc(v.z, lt[4 * c + 2], ac2);
      ac3 = dot2acc(v.w, lt[4 * c + 3], ac3);
    }
    // drain reads before next iteration's ds_write reuses the buffer
    asm volatile("s_waitcnt lgkmcnt(0)" ::: "memory");
    __builtin_nontemporal_store((ac0 + ac1) + (ac2 + ac3),
                                &out[(long)i * DO + lane]);
  }
}

extern "C" void kernel_launch(void* const* d_in, const int* in_sizes, int n_in,
                              void* d_out, int out_size, void* d_ws, size_t ws_size,
                              hipStream_t stream) {
  const float* x      = (const float*)d_in[0];
  const int*   eidx   = (const int*)d_in[1];
  const float* ew     = (const float*)d_in[2];
  const float* init_w = (const float*)d_in[3];
  const float* w_ih   = (const float*)d_in[4];
  const float* w_hh   = (const float*)d_in[5];
  const float* b_ih   = (const float*)d_in[6];
  const float* b_hh   = (const float*)d_in[7];
  const float* lin_w  = (const float*)d_in[8];
  const float* lin_b  = (const float*)d_in[9];
  float* out = (float*)d_out;
  const int* row = eidx;       // edge_index[0] = source j
  const int* col = eidx + NE;  // edge_index[1] = target i

  // workspace layout (4-byte units; offsets multiples of 64 -> 256B aligned)
  float* ws    = (float*)d_ws;
  float* W     = ws;                           // 16384
  unsigned long long* packed = (unsigned long long*)(W + 16384);  // 50048 u64
  float* dis   = (float*)(packed + 50048);     // 50048
  int*   cnt   = (int*)(dis + 50048);          // 50048
  int*   strt  = cnt + 50048;                  // 50048
  int*   total = strt + 50048;                 // 64
  int*   rank  = total + 64;                   // 800000
  unsigned int* epack = (unsigned int*)(rank + NE);  // <=1000064 u32 (padded x4)
  __half* ywh  = (__half*)(epack + 1000064);   // 6,400,000 half (12.8 MB)

  setup_kernel<<<64 + (NN + 255) / 256, 256, 0, stream>>>(init_w, w_ih, w_hh, b_ih,
                                                          b_hh, W, packed, total);
  count_deg_kernel<<<(NE + 255) / 256, 256, 0, stream>>>(col, ew, packed, rank);
  dis_scan_kernel<<<(NN + 255) / 256, 256, 0, stream>>>(packed, dis, cnt, strt, total);
  bucket_kernel<<<(NE + 255) / 256, 256, 0, stream>>>(row, col, ew, rank, strt, epack);
  xw_kernel<<<512, 256, 0, stream>>>(x, W, dis, ywh);
  gather_out_kernel<<<2048, 256, 0, stream>>>(strt, cnt, epack, dis, ywh,
                                              lin_w, lin_b, out);
}

// Round 9
// 233.435 us; speedup vs baseline: 1.0509x; 1.0509x over previous
//
#include <hip/hip_runtime.h>
#include <hip/hip_fp16.h>
#include <math.h>

// Problem constants (fixed by reference setup_inputs)
#define NN 50000      // nodes
#define NE 800000     // edges
#define D  128        // d_in
#define D3 384        // 3*d_in
#define DO 64         // d_out

typedef _Float16 f16x2 __attribute__((ext_vector_type(2)));

__device__ __forceinline__ float dot2acc(unsigned int h2bits, unsigned int wbits,
                                         float acc) {
#if __has_builtin(__builtin_amdgcn_fdot2)
  return __builtin_amdgcn_fdot2(__builtin_bit_cast(f16x2, h2bits),
                                __builtin_bit_cast(f16x2, wbits), acc, false);
#else
  float2 hf = __half22float2(__builtin_bit_cast(__half2, h2bits));
  float2 wf = __half22float2(__builtin_bit_cast(__half2, wbits));
  return acc + hf.x * wf.x + hf.y * wf.y;
#endif
}

// ---------------- setup: fused GRU (blocks 0..63) + init packed (blocks 64..) ------
__global__ __launch_bounds__(256) void setup_kernel(
    const float* __restrict__ init_w, const float* __restrict__ w_ih,
    const float* __restrict__ w_hh, const float* __restrict__ b_ih,
    const float* __restrict__ b_hh, float* __restrict__ W,
    unsigned long long* __restrict__ packed, int* __restrict__ total) {
  if (blockIdx.x >= 64) {
    int i = (blockIdx.x - 64) * 256 + threadIdx.x;
    if (i < NN) packed[i] = (1ULL << 32);  // deg = 1.0 fixed-point, count = 0
    if (i == 0) *total = 0;
    return;
  }
  int idx = blockIdx.x * 256 + threadIdx.x;  // < 16384
  int b = idx >> 7;
  int j = idx & 127;
  const float* xr = init_w + b * D;
  const float* wr_i = w_ih + j * D;
  const float* wz_i = w_ih + (D + j) * D;
  const float* wn_i = w_ih + (2 * D + j) * D;
  const float* wr_h = w_hh + j * D;
  const float* wz_h = w_hh + (D + j) * D;
  const float* wn_h = w_hh + (2 * D + j) * D;
  float ir = 0.f, iz = 0.f, in_ = 0.f, hr = 0.f, hz = 0.f, hn = 0.f;
#pragma unroll 4
  for (int k = 0; k < D; ++k) {
    float xv = xr[k];
    ir += xv * wr_i[k];
    iz += xv * wz_i[k];
    in_ += xv * wn_i[k];
    hr += xv * wr_h[k];
    hz += xv * wz_h[k];
    hn += xv * wn_h[k];
  }
  ir += b_ih[j];       hr += b_hh[j];
  iz += b_ih[D + j];   hz += b_hh[D + j];
  in_ += b_ih[2 * D + j]; hn += b_hh[2 * D + j];
  float r = 1.f / (1.f + expf(-(ir + hr)));
  float z = 1.f / (1.f + expf(-(iz + hz)));
  float n = tanhf(in_ + r * hn);
  W[idx] = (1.f - z) * n + z * init_w[idx];
}

// ---------------- one packed atomic per edge: count + fixed-point degree; rank -----
__global__ __launch_bounds__(256) void count_deg_kernel(const int* __restrict__ col,
                                                        const float* __restrict__ ew,
                                                        unsigned long long* __restrict__ packed,
                                                        int* __restrict__ rank) {
  int e = blockIdx.x * 256 + threadIdx.x;
  if (e < NE) {
    int c = __builtin_nontemporal_load(&col[e]);
    float w = __builtin_nontemporal_load(&ew[e]);
    unsigned long long add = (1ULL << 40) | (unsigned long long)(w * 4294967296.0f);
    unsigned long long old = atomicAdd(&packed[c], add);
    __builtin_nontemporal_store((int)(old >> 40), &rank[e]);
  }
}

// ---------------- dis = rsqrt(deg); cnt; bucket starts padded to x4 ----------------
__global__ __launch_bounds__(256) void dis_scan_kernel(
    const unsigned long long* __restrict__ packed, float* __restrict__ dis,
    int* __restrict__ cnt, int* __restrict__ start, int* __restrict__ total) {
  int i = blockIdx.x * 256 + threadIdx.x;
  int lane = threadIdx.x & 63;
  int c = 0;
  float d = 1.0f;
  if (i < NN) {
    unsigned long long p = packed[i];
    c = (int)(p >> 40);
    d = (float)(p & ((1ULL << 40) - 1)) * 0x1p-32f;
  }
  int cp = (c + 3) & ~3;  // pad buckets to multiple of 4 -> 16B-aligned u32 starts
  int pre = cp;
#pragma unroll
  for (int off = 1; off < 64; off <<= 1) {
    int t = __shfl_up(pre, off, 64);
    if (lane >= off) pre += t;
  }
  int excl = pre - cp;
  int wtot = __shfl(pre, 63, 64);
  int base = 0;
  if (lane == 63) base = atomicAdd(total, wtot);
  base = __shfl(base, 63, 64);
  if (i < NN) {
    start[i] = base + excl;
    cnt[i] = c;
    dis[i] = rsqrtf(fmaxf(d, 1e-12f));  // d >= 1.0 always (self-loop)
  }
}

// ---------------- bucket scatter, NO atomics: epack[slot] = (j:u16 | ew:f16<<16) ---
__global__ __launch_bounds__(256) void bucket_kernel(
    const int* __restrict__ row, const int* __restrict__ col,
    const float* __restrict__ ew, const int* __restrict__ rank,
    const int* __restrict__ start, unsigned int* __restrict__ epack) {
  int e = blockIdx.x * 256 + threadIdx.x;
  if (e >= NE) return;
  int j = __builtin_nontemporal_load(&row[e]);
  int c = __builtin_nontemporal_load(&col[e]);
  float w = __builtin_nontemporal_load(&ew[e]);
  int rk = __builtin_nontemporal_load(&rank[e]);
  unsigned short wb = __builtin_bit_cast(unsigned short, (_Float16)w);
  int slot = start[c] + rk;
  __builtin_nontemporal_store((unsigned int)j | ((unsigned int)wb << 16),
                              &epack[slot]);
}

// ---------------- yw = dis[r] * (x @ W)  -> fp16 (W staged in LDS) -----------------
struct alignas(16) h2x4 { __half2 a, b, c, d; };

__global__ __launch_bounds__(256) void xw_kernel(const float* __restrict__ x,
                                                 const float* __restrict__ W,
                                                 const float* __restrict__ dis,
                                                 __half* __restrict__ ywh) {
  __shared__ float Wl[D * D];  // 64 KB
  for (int i = threadIdx.x; i < D * D; i += 256) Wl[i] = W[i];
  __syncthreads();
  const int t = threadIdx.x;
  const int rr = t >> 4;           // 0..15
  const int c0 = (t & 15) * 8;     // 0..120
  const int ROWS_PER_TILE = 64;
  for (int base = blockIdx.x * ROWS_PER_TILE; base < NN; base += gridDim.x * ROWS_PER_TILE) {
    float acc[4][8];
#pragma unroll
    for (int q = 0; q < 4; ++q)
#pragma unroll
      for (int j = 0; j < 8; ++j) acc[q][j] = 0.f;
    int r0 = base + rr;
#pragma unroll 4
    for (int k = 0; k < D; ++k) {
      float xv[4];
#pragma unroll
      for (int q = 0; q < 4; ++q) {
        int r = r0 + q * 16;
        xv[q] = (r < NN) ? x[(long)r * D + k] : 0.f;
      }
#pragma unroll
      for (int j = 0; j < 8; ++j) {
        float wv = Wl[k * D + c0 + j];
#pragma unroll
        for (int q = 0; q < 4; ++q) acc[q][j] += xv[q] * wv;
      }
    }
#pragma unroll
    for (int q = 0; q < 4; ++q) {
      int r = r0 + q * 16;
      if (r < NN) {
        float ds = dis[r];
        h2x4 pk;
        pk.a = __floats2half2_rn(ds * acc[q][0], ds * acc[q][1]);
        pk.b = __floats2half2_rn(ds * acc[q][2], ds * acc[q][3]);
        pk.c = __floats2half2_rn(ds * acc[q][4], ds * acc[q][5]);
        pk.d = __floats2half2_rn(ds * acc[q][6], ds * acc[q][7]);
        *(h2x4*)(ywh + (long)r * D + c0) = pk;
      }
    }
  }
}

// ---------------- fused: gather (regs) -> relu -> LDS -> @ lin_w^T + b -------------
// h_i = relu(dis_i * (yw_i + sum ew*yw_j)). One wave per node; lane l holds dims
// (2l,2l+1) during gather; lane o = output channel in projection. lin_w lives in
// LDS as packed half2 [kk][o] (16 KB) -> low VGPR, high occupancy (R4-proven).
__global__ __launch_bounds__(256) void gather_out_kernel(
    const int* __restrict__ start, const int* __restrict__ cnt,
    const unsigned int* __restrict__ epack, const float* __restrict__ dis,
    const __half* __restrict__ ywh, const float* __restrict__ lin_w,
    const float* __restrict__ lin_b, float* __restrict__ out) {
  __shared__ unsigned int LTh[64 * 64];  // [kk][o] packed half2, 16 KB
  __shared__ unsigned int hb[4][64];     // per-wave packed-half2 h row, 1 KB
  for (int idx = threadIdx.x; idx < 64 * 64; idx += 256) {
    int kk = idx >> 6, o = idx & 63;
    __half2 w2 = __floats2half2_rn(lin_w[o * D + 2 * kk], lin_w[o * D + 2 * kk + 1]);
    LTh[idx] = __builtin_bit_cast(unsigned int, w2);
  }
  __syncthreads();
  const int wv = threadIdx.x >> 6;
  const int lane = threadIdx.x & 63;
  const float bias = lin_b[lane];
  const __half2* __restrict__ yw2 = (const __half2*)ywh;  // row stride 64
  int gw = blockIdx.x * 4 + wv;
  int nw = gridDim.x * 4;
  for (int i = gw; i < NN; i += nw) {
    // self-loop term: yw_i (weight 1)
    float2 sv = __half22float2(yw2[(long)i * 64 + lane]);
    float a0 = sv.x;
    float a1 = sv.y;
    int s = start[i];          // multiple of 4 -> epack+s is 16B aligned
    int se = s + cnt[i];
    for (; s + 4 <= se; s += 4) {
      uint4 p = *(const uint4*)(epack + s);  // 4 edges
      int j0 = p.x & 0xffff, j1 = p.y & 0xffff, j2 = p.z & 0xffff, j3 = p.w & 0xffff;
      _Float16 w0 = __builtin_bit_cast(_Float16, (unsigned short)(p.x >> 16));
      _Float16 w1 = __builtin_bit_cast(_Float16, (unsigned short)(p.y >> 16));
      _Float16 w2 = __builtin_bit_cast(_Float16, (unsigned short)(p.z >> 16));
      _Float16 w3 = __builtin_bit_cast(_Float16, (unsigned short)(p.w >> 16));
      __half2 v0 = yw2[(long)j0 * 64 + lane];
      __half2 v1 = yw2[(long)j1 * 64 + lane];
      __half2 v2 = yw2[(long)j2 * 64 + lane];
      __half2 v3 = yw2[(long)j3 * 64 + lane];
      // (float)f16 * (float)f16 + f32  ->  v_fma_mix_f32
      a0 += (float)w0 * (float)__low2half(v0) + (float)w1 * (float)__low2half(v1);
      a0 += (float)w2 * (float)__low2half(v2) + (float)w3 * (float)__low2half(v3);
      a1 += (float)w0 * (float)__high2half(v0) + (float)w1 * (float)__high2half(v1);
      a1 += (float)w2 * (float)__high2half(v2) + (float)w3 * (float)__high2half(v3);
    }
    for (; s < se; ++s) {
      unsigned int p = epack[s];
      int j0 = p & 0xffff;
      _Float16 w0 = __builtin_bit_cast(_Float16, (unsigned short)(p >> 16));
      __half2 v0 = yw2[(long)j0 * 64 + lane];
      a0 += (float)w0 * (float)__low2half(v0);
      a1 += (float)w0 * (float)__high2half(v0);
    }
    float ds = dis[i];
    __half2 hv = __floats2half2_rn(fmaxf(ds * a0, 0.f), fmaxf(ds * a1, 0.f));
    hb[wv][lane] = __builtin_bit_cast(unsigned int, hv);
    // same-wave LDS RAW: drain ds_write before reads (no cross-wave sharing)
    asm volatile("s_waitcnt lgkmcnt(0)" ::: "memory");
    float ac0 = bias, ac1 = 0.f, ac2 = 0.f, ac3 = 0.f;
    const uint4* hrow = (const uint4*)&hb[wv][0];
#pragma unroll
    for (int c = 0; c < 16; ++c) {
      uint4 v = hrow[c];  // broadcast b128 read, conflict-free
      ac0 = dot2acc(v.x, LTh[(4 * c + 0) * 64 + lane], ac0);
      ac1 = dot2acc(v.y, LTh[(4 * c + 1) * 64 + lane], ac1);
      ac2 = dot2acc(v.z, LTh[(4 * c + 2) * 64 + lane], ac2);
      ac3 = dot2acc(v.w, LTh[(4 * c + 3) * 64 + lane], ac3);
    }
    // drain reads before next iteration's ds_write reuses the buffer
    asm volatile("s_waitcnt lgkmcnt(0)" ::: "memory");
    __builtin_nontemporal_store((ac0 + ac1) + (ac2 + ac3),
                                &out[(long)i * DO + lane]);
  }
}

extern "C" void kernel_launch(void* const* d_in, const int* in_sizes, int n_in,
                              void* d_out, int out_size, void* d_ws, size_t ws_size,
                              hipStream_t stream) {
  const float* x      = (const float*)d_in[0];
  const int*   eidx   = (const int*)d_in[1];
  const float* ew     = (const float*)d_in[2];
  const float* init_w = (const float*)d_in[3];
  const float* w_ih   = (const float*)d_in[4];
  const float* w_hh   = (const float*)d_in[5];
  const float* b_ih   = (const float*)d_in[6];
  const float* b_hh   = (const float*)d_in[7];
  const float* lin_w  = (const float*)d_in[8];
  const float* lin_b  = (const float*)d_in[9];
  float* out = (float*)d_out;
  const int* row = eidx;       // edge_index[0] = source j
  const int* col = eidx + NE;  // edge_index[1] = target i

  // workspace layout (4-byte units; offsets multiples of 64 -> 256B aligned)
  float* ws    = (float*)d_ws;
  float* W     = ws;                           // 16384
  unsigned long long* packed = (unsigned long long*)(W + 16384);  // 50048 u64
  float* dis   = (float*)(packed + 50048);     // 50048
  int*   cnt   = (int*)(dis + 50048);          // 50048
  int*   strt  = cnt + 50048;                  // 50048
  int*   total = strt + 50048;                 // 64
  int*   rank  = total + 64;                   // 800000
  unsigned int* epack = (unsigned int*)(rank + NE);  // <=1000064 u32 (padded x4)
  __half* ywh  = (__half*)(epack + 1000064);   // 6,400,000 half (12.8 MB)

  setup_kernel<<<64 + (NN + 255) / 256, 256, 0, stream>>>(init_w, w_ih, w_hh, b_ih,
                                                          b_hh, W, packed, total);
  count_deg_kernel<<<(NE + 255) / 256, 256, 0, stream>>>(col, ew, packed, rank);
  dis_scan_kernel<<<(NN + 255) / 256, 256, 0, stream>>>(packed, dis, cnt, strt, total);
  bucket_kernel<<<(NE + 255) / 256, 256, 0, stream>>>(row, col, ew, rank, strt, epack);
  xw_kernel<<<512, 256, 0, stream>>>(x, W, dis, ywh);
  gather_out_kernel<<<2048, 256, 0, stream>>>(strt, cnt, epack, dis, ywh,
                                              lin_w, lin_b, out);
}

// Round 10
// 203.017 us; speedup vs baseline: 1.2084x; 1.1498x over previous
//
#include <hip/hip_runtime.h>
#include <hip/hip_fp16.h>
#include <math.h>

// Problem constants (fixed by reference setup_inputs)
#define NN 50000      // nodes
#define NE 800000     // edges
#define D  128        // d_in
#define D3 384        // 3*d_in
#define DO 64         // d_out

typedef _Float16 f16x2 __attribute__((ext_vector_type(2)));

__device__ __forceinline__ float dot2acc(unsigned int h2bits, unsigned int wbits,
                                         float acc) {
#if __has_builtin(__builtin_amdgcn_fdot2)
  return __builtin_amdgcn_fdot2(__builtin_bit_cast(f16x2, h2bits),
                                __builtin_bit_cast(f16x2, wbits), acc, false);
#else
  float2 hf = __half22float2(__builtin_bit_cast(__half2, h2bits));
  float2 wf = __half22float2(__builtin_bit_cast(__half2, wbits));
  return acc + hf.x * wf.x + hf.y * wf.y;
#endif
}

// ---------------- setup: fused GRU (blocks 0..63) + init packed (blocks 64..) ------
__global__ __launch_bounds__(256) void setup_kernel(
    const float* __restrict__ init_w, const float* __restrict__ w_ih,
    const float* __restrict__ w_hh, const float* __restrict__ b_ih,
    const float* __restrict__ b_hh, float* __restrict__ W,
    unsigned long long* __restrict__ packed, int* __restrict__ total) {
  if (blockIdx.x >= 64) {
    int i = (blockIdx.x - 64) * 256 + threadIdx.x;
    if (i < NN) packed[i] = (1ULL << 32);  // deg = 1.0 fixed-point, count = 0
    if (i == 0) *total = 0;
    return;
  }
  int idx = blockIdx.x * 256 + threadIdx.x;  // < 16384
  int b = idx >> 7;
  int j = idx & 127;
  const float* xr = init_w + b * D;
  const float* wr_i = w_ih + j * D;
  const float* wz_i = w_ih + (D + j) * D;
  const float* wn_i = w_ih + (2 * D + j) * D;
  const float* wr_h = w_hh + j * D;
  const float* wz_h = w_hh + (D + j) * D;
  const float* wn_h = w_hh + (2 * D + j) * D;
  float ir = 0.f, iz = 0.f, in_ = 0.f, hr = 0.f, hz = 0.f, hn = 0.f;
#pragma unroll 4
  for (int k = 0; k < D; ++k) {
    float xv = xr[k];
    ir += xv * wr_i[k];
    iz += xv * wz_i[k];
    in_ += xv * wn_i[k];
    hr += xv * wr_h[k];
    hz += xv * wz_h[k];
    hn += xv * wn_h[k];
  }
  ir += b_ih[j];       hr += b_hh[j];
  iz += b_ih[D + j];   hz += b_hh[D + j];
  in_ += b_ih[2 * D + j]; hn += b_hh[2 * D + j];
  float r = 1.f / (1.f + expf(-(ir + hr)));
  float z = 1.f / (1.f + expf(-(iz + hz)));
  float n = tanhf(in_ + r * hn);
  W[idx] = (1.f - z) * n + z * init_w[idx];
}

// ---------------- one packed atomic per edge: count + fixed-point degree; rank -----
__global__ __launch_bounds__(256) void count_deg_kernel(const int* __restrict__ col,
                                                        const float* __restrict__ ew,
                                                        unsigned long long* __restrict__ packed,
                                                        int* __restrict__ rank) {
  int e = blockIdx.x * 256 + threadIdx.x;
  if (e < NE) {
    int c = __builtin_nontemporal_load(&col[e]);
    float w = __builtin_nontemporal_load(&ew[e]);
    unsigned long long add = (1ULL << 40) | (unsigned long long)(w * 4294967296.0f);
    unsigned long long old = atomicAdd(&packed[c], add);
    __builtin_nontemporal_store((int)(old >> 40), &rank[e]);
  }
}

// ---------------- dis = rsqrt(deg); cnt; bucket starts padded to x4 ----------------
__global__ __launch_bounds__(256) void dis_scan_kernel(
    const unsigned long long* __restrict__ packed, float* __restrict__ dis,
    int* __restrict__ cnt, int* __restrict__ start, int* __restrict__ total) {
  int i = blockIdx.x * 256 + threadIdx.x;
  int lane = threadIdx.x & 63;
  int c = 0;
  float d = 1.0f;
  if (i < NN) {
    unsigned long long p = packed[i];
    c = (int)(p >> 40);
    d = (float)(p & ((1ULL << 40) - 1)) * 0x1p-32f;
  }
  int cp = (c + 3) & ~3;  // pad buckets to multiple of 4 -> 16B-aligned u32 starts
  int pre = cp;
#pragma unroll
  for (int off = 1; off < 64; off <<= 1) {
    int t = __shfl_up(pre, off, 64);
    if (lane >= off) pre += t;
  }
  int excl = pre - cp;
  int wtot = __shfl(pre, 63, 64);
  int base = 0;
  if (lane == 63) base = atomicAdd(total, wtot);
  base = __shfl(base, 63, 64);
  if (i < NN) {
    start[i] = base + excl;
    cnt[i] = c;
    dis[i] = rsqrtf(fmaxf(d, 1e-12f));  // d >= 1.0 always (self-loop)
  }
}

// ---------------- bucket scatter, NO atomics: epack[slot] = (j:u16 | ew:f16<<16) ---
__global__ __launch_bounds__(256) void bucket_kernel(
    const int* __restrict__ row, const int* __restrict__ col,
    const float* __restrict__ ew, const int* __restrict__ rank,
    const int* __restrict__ start, unsigned int* __restrict__ epack) {
  int e = blockIdx.x * 256 + threadIdx.x;
  if (e >= NE) return;
  int j = __builtin_nontemporal_load(&row[e]);
  int c = __builtin_nontemporal_load(&col[e]);
  float w = __builtin_nontemporal_load(&ew[e]);
  int rk = __builtin_nontemporal_load(&rank[e]);
  unsigned short wb = __builtin_bit_cast(unsigned short, (_Float16)w);
  int slot = start[c] + rk;
  __builtin_nontemporal_store((unsigned int)j | ((unsigned int)wb << 16),
                              &epack[slot]);
}

// ---------------- yw = dis[r] * (x @ W)  -> fp16 (W staged in LDS) -----------------
struct alignas(16) h2x4 { __half2 a, b, c, d; };

__global__ __launch_bounds__(256) void xw_kernel(const float* __restrict__ x,
                                                 const float* __restrict__ W,
                                                 const float* __restrict__ dis,
                                                 __half* __restrict__ ywh) {
  __shared__ float Wl[D * D];  // 64 KB
  for (int i = threadIdx.x; i < D * D; i += 256) Wl[i] = W[i];
  __syncthreads();
  const int t = threadIdx.x;
  const int rr = t >> 4;           // 0..15
  const int c0 = (t & 15) * 8;     // 0..120
  const int ROWS_PER_TILE = 64;
  for (int base = blockIdx.x * ROWS_PER_TILE; base < NN; base += gridDim.x * ROWS_PER_TILE) {
    float acc[4][8];
#pragma unroll
    for (int q = 0; q < 4; ++q)
#pragma unroll
      for (int j = 0; j < 8; ++j) acc[q][j] = 0.f;
    int r0 = base + rr;
#pragma unroll 4
    for (int k = 0; k < D; ++k) {
      float xv[4];
#pragma unroll
      for (int q = 0; q < 4; ++q) {
        int r = r0 + q * 16;
        xv[q] = (r < NN) ? x[(long)r * D + k] : 0.f;
      }
#pragma unroll
      for (int j = 0; j < 8; ++j) {
        float wv = Wl[k * D + c0 + j];
#pragma unroll
        for (int q = 0; q < 4; ++q) acc[q][j] += xv[q] * wv;
      }
    }
#pragma unroll
    for (int q = 0; q < 4; ++q) {
      int r = r0 + q * 16;
      if (r < NN) {
        float ds = dis[r];
        h2x4 pk;
        pk.a = __floats2half2_rn(ds * acc[q][0], ds * acc[q][1]);
        pk.b = __floats2half2_rn(ds * acc[q][2], ds * acc[q][3]);
        pk.c = __floats2half2_rn(ds * acc[q][4], ds * acc[q][5]);
        pk.d = __floats2half2_rn(ds * acc[q][6], ds * acc[q][7]);
        *(h2x4*)(ywh + (long)r * D + c0) = pk;
      }
    }
  }
}

// ---------------- fused dual-node gather -> relu -> LDS -> @ lin_w^T + b -----------
// h_i = relu(dis_i * (yw_i + sum ew*yw_j)). One wave handles TWO nodes (i, i+nw)
// per iteration with interleaved edge loops -> 2x outstanding loads (latency-bound
// fix). Lane l holds dims (2l,2l+1) during gather; lane o = out channel in
// projection; lin_w in LDS as packed half2 (low VGPR, high occupancy).
__global__ __launch_bounds__(256) void gather_out_kernel(
    const int* __restrict__ start, const int* __restrict__ cnt,
    const unsigned int* __restrict__ epack, const float* __restrict__ dis,
    const __half* __restrict__ ywh, const float* __restrict__ lin_w,
    const float* __restrict__ lin_b, float* __restrict__ out) {
  __shared__ unsigned int LTh[64 * 64];  // [kk][o] packed half2, 16 KB
  __shared__ unsigned int hb[4][2][64];  // per-wave packed-half2 h rows (A,B), 2 KB
  for (int idx = threadIdx.x; idx < 64 * 64; idx += 256) {
    int kk = idx >> 6, o = idx & 63;
    __half2 w2 = __floats2half2_rn(lin_w[o * D + 2 * kk], lin_w[o * D + 2 * kk + 1]);
    LTh[idx] = __builtin_bit_cast(unsigned int, w2);
  }
  __syncthreads();
  const int wv = threadIdx.x >> 6;
  const int lane = threadIdx.x & 63;
  const float bias = lin_b[lane];
  const __half2* __restrict__ yw2 = (const __half2*)ywh;  // row stride 64
  int gw = blockIdx.x * 4 + wv;
  int nw = gridDim.x * 4;
  for (int i = gw; i < NN; i += 2 * nw) {
    const int iB = i + nw;
    const bool hasB = iB < NN;
    // self-loop terms: yw_i (weight 1)
    float2 svA = __half22float2(yw2[(long)i * 64 + lane]);
    float aA0 = svA.x, aA1 = svA.y;
    float aB0 = 0.f, aB1 = 0.f;
    int sA = start[i], seA = sA + cnt[i];
    int sB = 0, seB = 0;
    if (hasB) {
      float2 svB = __half22float2(yw2[(long)iB * 64 + lane]);
      aB0 = svB.x;
      aB1 = svB.y;
      sB = start[iB];
      seB = sB + cnt[iB];
    }
    // interleaved main loops: 2 packet loads + 8 gathers in flight
    while (sA + 4 <= seA && sB + 4 <= seB) {
      uint4 pA = *(const uint4*)(epack + sA);
      uint4 pB = *(const uint4*)(epack + sB);
      __half2 vA0 = yw2[(long)(pA.x & 0xffff) * 64 + lane];
      __half2 vA1 = yw2[(long)(pA.y & 0xffff) * 64 + lane];
      __half2 vA2 = yw2[(long)(pA.z & 0xffff) * 64 + lane];
      __half2 vA3 = yw2[(long)(pA.w & 0xffff) * 64 + lane];
      __half2 vB0 = yw2[(long)(pB.x & 0xffff) * 64 + lane];
      __half2 vB1 = yw2[(long)(pB.y & 0xffff) * 64 + lane];
      __half2 vB2 = yw2[(long)(pB.z & 0xffff) * 64 + lane];
      __half2 vB3 = yw2[(long)(pB.w & 0xffff) * 64 + lane];
      _Float16 wA0 = __builtin_bit_cast(_Float16, (unsigned short)(pA.x >> 16));
      _Float16 wA1 = __builtin_bit_cast(_Float16, (unsigned short)(pA.y >> 16));
      _Float16 wA2 = __builtin_bit_cast(_Float16, (unsigned short)(pA.z >> 16));
      _Float16 wA3 = __builtin_bit_cast(_Float16, (unsigned short)(pA.w >> 16));
      _Float16 wB0 = __builtin_bit_cast(_Float16, (unsigned short)(pB.x >> 16));
      _Float16 wB1 = __builtin_bit_cast(_Float16, (unsigned short)(pB.y >> 16));
      _Float16 wB2 = __builtin_bit_cast(_Float16, (unsigned short)(pB.z >> 16));
      _Float16 wB3 = __builtin_bit_cast(_Float16, (unsigned short)(pB.w >> 16));
      aA0 += (float)wA0 * (float)__low2half(vA0) + (float)wA1 * (float)__low2half(vA1) +
             (float)wA2 * (float)__low2half(vA2) + (float)wA3 * (float)__low2half(vA3);
      aA1 += (float)wA0 * (float)__high2half(vA0) + (float)wA1 * (float)__high2half(vA1) +
             (float)wA2 * (float)__high2half(vA2) + (float)wA3 * (float)__high2half(vA3);
      aB0 += (float)wB0 * (float)__low2half(vB0) + (float)wB1 * (float)__low2half(vB1) +
             (float)wB2 * (float)__low2half(vB2) + (float)wB3 * (float)__low2half(vB3);
      aB1 += (float)wB0 * (float)__high2half(vB0) + (float)wB1 * (float)__high2half(vB1) +
             (float)wB2 * (float)__high2half(vB2) + (float)wB3 * (float)__high2half(vB3);
      sA += 4;
      sB += 4;
    }
    for (; sA + 4 <= seA; sA += 4) {
      uint4 p = *(const uint4*)(epack + sA);
      __half2 v0 = yw2[(long)(p.x & 0xffff) * 64 + lane];
      __half2 v1 = yw2[(long)(p.y & 0xffff) * 64 + lane];
      __half2 v2 = yw2[(long)(p.z & 0xffff) * 64 + lane];
      __half2 v3 = yw2[(long)(p.w & 0xffff) * 64 + lane];
      _Float16 w0 = __builtin_bit_cast(_Float16, (unsigned short)(p.x >> 16));
      _Float16 w1 = __builtin_bit_cast(_Float16, (unsigned short)(p.y >> 16));
      _Float16 w2 = __builtin_bit_cast(_Float16, (unsigned short)(p.z >> 16));
      _Float16 w3 = __builtin_bit_cast(_Float16, (unsigned short)(p.w >> 16));
      aA0 += (float)w0 * (float)__low2half(v0) + (float)w1 * (float)__low2half(v1) +
             (float)w2 * (float)__low2half(v2) + (float)w3 * (float)__low2half(v3);
      aA1 += (float)w0 * (float)__high2half(v0) + (float)w1 * (float)__high2half(v1) +
             (float)w2 * (float)__high2half(v2) + (float)w3 * (float)__high2half(v3);
    }
    for (; sA < seA; ++sA) {
      unsigned int p = epack[sA];
      _Float16 w0 = __builtin_bit_cast(_Float16, (unsigned short)(p >> 16));
      __half2 v0 = yw2[(long)(p & 0xffff) * 64 + lane];
      aA0 += (float)w0 * (float)__low2half(v0);
      aA1 += (float)w0 * (float)__high2half(v0);
    }
    for (; sB + 4 <= seB; sB += 4) {
      uint4 p = *(const uint4*)(epack + sB);
      __half2 v0 = yw2[(long)(p.x & 0xffff) * 64 + lane];
      __half2 v1 = yw2[(long)(p.y & 0xffff) * 64 + lane];
      __half2 v2 = yw2[(long)(p.z & 0xffff) * 64 + lane];
      __half2 v3 = yw2[(long)(p.w & 0xffff) * 64 + lane];
      _Float16 w0 = __builtin_bit_cast(_Float16, (unsigned short)(p.x >> 16));
      _Float16 w1 = __builtin_bit_cast(_Float16, (unsigned short)(p.y >> 16));
      _Float16 w2 = __builtin_bit_cast(_Float16, (unsigned short)(p.z >> 16));
      _Float16 w3 = __builtin_bit_cast(_Float16, (unsigned short)(p.w >> 16));
      aB0 += (float)w0 * (float)__low2half(v0) + (float)w1 * (float)__low2half(v1) +
             (float)w2 * (float)__low2half(v2) + (float)w3 * (float)__low2half(v3);
      aB1 += (float)w0 * (float)__high2half(v0) + (float)w1 * (float)__high2half(v1) +
             (float)w2 * (float)__high2half(v2) + (float)w3 * (float)__high2half(v3);
    }
    for (; sB < seB; ++sB) {
      unsigned int p = epack[sB];
      _Float16 w0 = __builtin_bit_cast(_Float16, (unsigned short)(p >> 16));
      __half2 v0 = yw2[(long)(p & 0xffff) * 64 + lane];
      aB0 += (float)w0 * (float)__low2half(v0);
      aB1 += (float)w0 * (float)__high2half(v0);
    }
    // relu + pack; exchange both rows through LDS
    float dsA = dis[i];
    hb[wv][0][lane] = __builtin_bit_cast(
        unsigned int, __floats2half2_rn(fmaxf(dsA * aA0, 0.f), fmaxf(dsA * aA1, 0.f)));
    if (hasB) {
      float dsB = dis[iB];
      hb[wv][1][lane] = __builtin_bit_cast(
          unsigned int, __floats2half2_rn(fmaxf(dsB * aB0, 0.f), fmaxf(dsB * aB1, 0.f)));
    }
    // same-wave LDS RAW: drain ds_writes before reads (no cross-wave sharing)
    asm volatile("s_waitcnt lgkmcnt(0)" ::: "memory");
    {
      float ac0 = bias, ac1 = 0.f, ac2 = 0.f, ac3 = 0.f;
      const uint4* hrow = (const uint4*)&hb[wv][0][0];
#pragma unroll
      for (int c = 0; c < 16; ++c) {
        uint4 v = hrow[c];  // broadcast b128 read, conflict-free
        ac0 = dot2acc(v.x, LTh[(4 * c + 0) * 64 + lane], ac0);
        ac1 = dot2acc(v.y, LTh[(4 * c + 1) * 64 + lane], ac1);
        ac2 = dot2acc(v.z, LTh[(4 * c + 2) * 64 + lane], ac2);
        ac3 = dot2acc(v.w, LTh[(4 * c + 3) * 64 + lane], ac3);
      }
      __builtin_nontemporal_store((ac0 + ac1) + (ac2 + ac3),
                                  &out[(long)i * DO + lane]);
    }
    if (hasB) {
      float ac0 = bias, ac1 = 0.f, ac2 = 0.f, ac3 = 0.f;
      const uint4* hrow = (const uint4*)&hb[wv][1][0];
#pragma unroll
      for (int c = 0; c < 16; ++c) {
        uint4 v = hrow[c];
        ac0 = dot2acc(v.x, LTh[(4 * c + 0) * 64 + lane], ac0);
        ac1 = dot2acc(v.y, LTh[(4 * c + 1) * 64 + lane], ac1);
        ac2 = dot2acc(v.z, LTh[(4 * c + 2) * 64 + lane], ac2);
        ac3 = dot2acc(v.w, LTh[(4 * c + 3) * 64 + lane], ac3);
      }
      __builtin_nontemporal_store((ac0 + ac1) + (ac2 + ac3),
                                  &out[(long)iB * DO + lane]);
    }
    // drain reads before next iteration's ds_writes reuse the buffer
    asm volatile("s_waitcnt lgkmcnt(0)" ::: "memory");
  }
}

extern "C" void kernel_launch(void* const* d_in, const int* in_sizes, int n_in,
                              void* d_out, int out_size, void* d_ws, size_t ws_size,
                              hipStream_t stream) {
  const float* x      = (const float*)d_in[0];
  const int*   eidx   = (const int*)d_in[1];
  const float* ew     = (const float*)d_in[2];
  const float* init_w = (const float*)d_in[3];
  const float* w_ih   = (const float*)d_in[4];
  const float* w_hh   = (const float*)d_in[5];
  const float* b_ih   = (const float*)d_in[6];
  const float* b_hh   = (const float*)d_in[7];
  const float* lin_w  = (const float*)d_in[8];
  const float* lin_b  = (const float*)d_in[9];
  float* out = (float*)d_out;
  const int* row = eidx;       // edge_index[0] = source j
  const int* col = eidx + NE;  // edge_index[1] = target i

  // workspace layout (4-byte units; offsets multiples of 64 -> 256B aligned)
  float* ws    = (float*)d_ws;
  float* W     = ws;                           // 16384
  unsigned long long* packed = (unsigned long long*)(W + 16384);  // 50048 u64
  float* dis   = (float*)(packed + 50048);     // 50048
  int*   cnt   = (int*)(dis + 50048);          // 50048
  int*   strt  = cnt + 50048;                  // 50048
  int*   total = strt + 50048;                 // 64
  int*   rank  = total + 64;                   // 800000
  unsigned int* epack = (unsigned int*)(rank + NE);  // <=1000064 u32 (padded x4)
  __half* ywh  = (__half*)(epack + 1000064);   // 6,400,000 half (12.8 MB)

  setup_kernel<<<64 + (NN + 255) / 256, 256, 0, stream>>>(init_w, w_ih, w_hh, b_ih,
                                                          b_hh, W, packed, total);
  count_deg_kernel<<<(NE + 255) / 256, 256, 0, stream>>>(col, ew, packed, rank);
  dis_scan_kernel<<<(NN + 255) / 256, 256, 0, stream>>>(packed, dis, cnt, strt, total);
  bucket_kernel<<<(NE + 255) / 256, 256, 0, stream>>>(row, col, ew, rank, strt, epack);
  xw_kernel<<<512, 256, 0, stream>>>(x, W, dis, ywh);
  gather_out_kernel<<<2048, 256, 0, stream>>>(strt, cnt, epack, dis, ywh,
                                              lin_w, lin_b, out);
}